// Round 1
// baseline (379.431 us; speedup 1.0000x reference)
//
#include <hip/hip_runtime.h>
#include <hip/hip_bf16.h>

typedef __attribute__((ext_vector_type(8))) short bf16x8;
typedef __attribute__((ext_vector_type(4))) float f32x4;

#define BB   64
#define LL   512
#define CIN  64
#define FF   128
#define KW   7
#define OUTL 506
#define LPAD 518        // 512 + 3 + 3
#define KC   448        // KW*CIN  (conv GEMM K)
#define KL   896        // KW*FF   (local GEMM K)
#define EPSV 1e-3f

static __device__ __forceinline__ short f2bf(float f) {
    // fp32 -> bf16, round-to-nearest-even
    unsigned u = __builtin_bit_cast(unsigned, f);
    unsigned r = (u + 0x7fffu + ((u >> 16) & 1u)) >> 16;
    return (short)r;
}

// ---------------------------------------------------------------- kernel 0
// zero-pad x by 3 on each side of L, cast to bf16.  x_pad: (B, 518, 64)
__global__ void pad_cvt_kernel(const float* __restrict__ x, short* __restrict__ xp) {
    int i = blockIdx.x * 256 + threadIdx.x;
    if (i >= BB * LPAD * CIN) return;
    int c  = i & (CIN - 1);
    int t  = i >> 6;            // b*LPAD + lp
    int lp = t % LPAD;
    int b  = t / LPAD;
    float v = 0.0f;
    int l = lp - 3;
    if (l >= 0 && l < LL) v = x[(b * LL + l) * CIN + c];
    xp[i] = f2bf(v);
}

// ---------------------------------------------------------------- kernel 1
// conv-as-GEMM: M = B*L (rows), K = 448, N = 128.  Fused BN1 + ReLU -> y bf16.
// block = 256 (4 waves). wave w: cols [32w, 32w+32), rows [m0, m0+64).
__global__ __launch_bounds__(256) void conv_bn_kernel(
    const short* __restrict__ xp, const float* __restrict__ w,
    const float* __restrict__ cb, const float* __restrict__ g,
    const float* __restrict__ be, const float* __restrict__ mu,
    const float* __restrict__ va, short* __restrict__ y) {
    const int lane = threadIdx.x & 63;
    const int wid  = threadIdx.x >> 6;
    const int m0   = blockIdx.x * 64;
    const int nb   = wid * 32;
    const int q    = lane >> 4;
    const int ln   = lane & 15;

    const short* arow[4];
#pragma unroll
    for (int mt = 0; mt < 4; ++mt) {
        int m = m0 + mt * 16 + ln;
        int b = m >> 9, l = m & 511;           // m = b*512 + l
        arow[mt] = xp + (b * LPAD + l) * CIN;  // 448 contiguous bf16 (padded)
    }

    f32x4 acc[4][2];
#pragma unroll
    for (int mt = 0; mt < 4; ++mt)
#pragma unroll
        for (int nt = 0; nt < 2; ++nt) acc[mt][nt] = (f32x4){0.f, 0.f, 0.f, 0.f};

#pragma unroll 2
    for (int kc = 0; kc < KC; kc += 32) {
        const int ko = kc + q * 8;
        bf16x8 a[4];
#pragma unroll
        for (int mt = 0; mt < 4; ++mt)
            a[mt] = *(const bf16x8*)(arow[mt] + ko);
        bf16x8 bf[2];
#pragma unroll
        for (int nt = 0; nt < 2; ++nt) {
            const int n = nb + nt * 16 + ln;
            const float* wp = w + (size_t)ko * FF + n;  // w[k][n], k-stride 128
#pragma unroll
            for (int j = 0; j < 8; ++j) bf[nt][j] = f2bf(wp[(size_t)j * FF]);
        }
#pragma unroll
        for (int mt = 0; mt < 4; ++mt)
#pragma unroll
            for (int nt = 0; nt < 2; ++nt)
                acc[mt][nt] = __builtin_amdgcn_mfma_f32_16x16x32_bf16(
                    a[mt], bf[nt], acc[mt][nt], 0, 0, 0);
    }

    // epilogue: + conv_b, BN1, ReLU, cast bf16
#pragma unroll
    for (int nt = 0; nt < 2; ++nt) {
        const int n = nb + nt * 16 + ln;
        const float s  = g[n] * rsqrtf(va[n] + EPSV);
        const float b2 = s * (cb[n] - mu[n]) + be[n];
#pragma unroll
        for (int mt = 0; mt < 4; ++mt) {
            const int mbase = m0 + mt * 16 + q * 4;
#pragma unroll
            for (int r = 0; r < 4; ++r) {
                float v = fmaxf(acc[mt][nt][r] * s + b2, 0.0f);
                y[(size_t)(mbase + r) * FF + n] = f2bf(v);
            }
        }
    }
}

// ---------------------------------------------------------------- kernel 2
// locally-connected: one block per output position l. C(64x128) = A(64x896)@W_l(896x128)
// A row b = y[b, l*128 .. l*128+896) contiguous bf16. W_l fp32 streamed once.
__global__ __launch_bounds__(256) void local_bn_kernel(
    const short* __restrict__ y, const float* __restrict__ lw,
    const float* __restrict__ lb, const float* __restrict__ g,
    const float* __restrict__ be, const float* __restrict__ mu,
    const float* __restrict__ va, float* __restrict__ out) {
    const int l    = blockIdx.x;
    const int lane = threadIdx.x & 63;
    const int wid  = threadIdx.x >> 6;
    const int nb   = wid * 32;
    const int q    = lane >> 4;
    const int ln   = lane & 15;

    const short* arow[4];
#pragma unroll
    for (int mt = 0; mt < 4; ++mt) {
        const int b = mt * 16 + ln;
        arow[mt] = y + (size_t)b * (LL * FF) + (size_t)l * FF;
    }
    const float* wl = lw + (size_t)l * (KL * FF);

    f32x4 acc[4][2];
#pragma unroll
    for (int mt = 0; mt < 4; ++mt)
#pragma unroll
        for (int nt = 0; nt < 2; ++nt) acc[mt][nt] = (f32x4){0.f, 0.f, 0.f, 0.f};

#pragma unroll 2
    for (int kc = 0; kc < KL; kc += 32) {
        const int ko = kc + q * 8;
        bf16x8 a[4];
#pragma unroll
        for (int mt = 0; mt < 4; ++mt)
            a[mt] = *(const bf16x8*)(arow[mt] + ko);
        bf16x8 bf[2];
#pragma unroll
        for (int nt = 0; nt < 2; ++nt) {
            const int n = nb + nt * 16 + ln;
            const float* wp = wl + (size_t)ko * FF + n;
#pragma unroll
            for (int j = 0; j < 8; ++j) bf[nt][j] = f2bf(wp[(size_t)j * FF]);
        }
#pragma unroll
        for (int mt = 0; mt < 4; ++mt)
#pragma unroll
            for (int nt = 0; nt < 2; ++nt)
                acc[mt][nt] = __builtin_amdgcn_mfma_f32_16x16x32_bf16(
                    a[mt], bf[nt], acc[mt][nt], 0, 0, 0);
    }

    // epilogue: + local_b[l], BN2, ReLU, fp32 store
#pragma unroll
    for (int nt = 0; nt < 2; ++nt) {
        const int n = nb + nt * 16 + ln;
        const float s  = g[n] * rsqrtf(va[n] + EPSV);
        const float b2 = s * (lb[(size_t)l * FF + n] - mu[n]) + be[n];
#pragma unroll
        for (int mt = 0; mt < 4; ++mt) {
            const int bbase = mt * 16 + q * 4;
#pragma unroll
            for (int r = 0; r < 4; ++r) {
                float v = fmaxf(acc[mt][nt][r] * s + b2, 0.0f);
                out[(size_t)(bbase + r) * (OUTL * FF) + (size_t)l * FF + n] = v;
            }
        }
    }
}

// ---------------------------------------------------------------- launch
extern "C" void kernel_launch(void* const* d_in, const int* in_sizes, int n_in,
                              void* d_out, int out_size, void* d_ws, size_t ws_size,
                              hipStream_t stream) {
    const float* x       = (const float*)d_in[0];
    const float* conv_w  = (const float*)d_in[1];
    const float* conv_b  = (const float*)d_in[2];
    const float* bn1_g   = (const float*)d_in[3];
    const float* bn1_b   = (const float*)d_in[4];
    const float* bn1_m   = (const float*)d_in[5];
    const float* bn1_v   = (const float*)d_in[6];
    const float* local_w = (const float*)d_in[7];
    const float* local_b = (const float*)d_in[8];
    const float* bn2_g   = (const float*)d_in[9];
    const float* bn2_b   = (const float*)d_in[10];
    const float* bn2_m   = (const float*)d_in[11];
    const float* bn2_v   = (const float*)d_in[12];
    float* out = (float*)d_out;

    short* xp  = (short*)d_ws;                  // (64, 518, 64) bf16
    short* ybf = xp + (size_t)BB * LPAD * CIN;  // (64, 512, 128) bf16

    const int npad = BB * LPAD * CIN;
    pad_cvt_kernel<<<(npad + 255) / 256, 256, 0, stream>>>(x, xp);
    conv_bn_kernel<<<(BB * LL) / 64, 256, 0, stream>>>(
        xp, conv_w, conv_b, bn1_g, bn1_b, bn1_m, bn1_v, ybf);
    local_bn_kernel<<<OUTL, 256, 0, stream>>>(
        ybf, local_w, local_b, bn2_g, bn2_b, bn2_m, bn2_v, out);
}

// Round 2
// 374.824 us; speedup vs baseline: 1.0123x; 1.0123x over previous
//
#include <hip/hip_runtime.h>
#include <hip/hip_bf16.h>

typedef __attribute__((ext_vector_type(8))) short bf16x8;
typedef __attribute__((ext_vector_type(4))) float f32x4;

#define BB   64
#define LL   512
#define CIN  64
#define FF   128
#define KW   7
#define OUTL 506
#define LPAD 518        // 512 + 3 + 3
#define KC   448        // KW*CIN  (conv GEMM K)
#define KL   896        // KW*FF   (local GEMM K)
#define BK   32         // local GEMM K-chunk staged in LDS
#define NCH  28         // KL / BK
#define EPSV 1e-3f

#define NPAD  (BB * LPAD * CIN)      // 2,121,728
#define PADB  (NPAD / 256)           // 8288 (exact)
#define NWT   (FF * KC)              // 57,344
#define WTB   (NWT / 256)            // 224 (exact)

static __device__ __forceinline__ short f2bf(float f) {
    // fp32 -> bf16, round-to-nearest-even
    unsigned u = __builtin_bit_cast(unsigned, f);
    unsigned r = (u + 0x7fffu + ((u >> 16) & 1u)) >> 16;
    return (short)r;
}

// async global->LDS, 16 B per lane; LDS dest = wave-uniform base + lane*16
static __device__ __forceinline__ void g2lds16(const float* g, float* l) {
    __builtin_amdgcn_global_load_lds(
        (const __attribute__((address_space(1))) unsigned int*)g,
        (__attribute__((address_space(3))) unsigned int*)l, 16, 0, 0);
}

// ---------------------------------------------------------------- kernel 0
// blocks [0, PADB): zero-pad x by 3 each side of L, cast bf16 -> xp (B,518,64)
// blocks [PADB, PADB+WTB): transpose+cast conv_w (448,128) -> wt[n][k] bf16
__global__ void prep_kernel(const float* __restrict__ x, const float* __restrict__ w,
                            short* __restrict__ xp, short* __restrict__ wt) {
    if (blockIdx.x < PADB) {
        int i = blockIdx.x * 256 + threadIdx.x;
        int c  = i & (CIN - 1);
        int t  = i >> 6;            // b*LPAD + lp
        int lp = t % LPAD;
        int b  = t / LPAD;
        float v = 0.0f;
        int l = lp - 3;
        if (l >= 0 && l < LL) v = x[(b * LL + l) * CIN + c];
        xp[i] = f2bf(v);
    } else {
        int i = (blockIdx.x - PADB) * 256 + threadIdx.x;  // < 57344
        int n = i / KC;
        int k = i - n * KC;
        wt[i] = f2bf(w[(size_t)k * FF + n]);
    }
}

// ---------------------------------------------------------------- kernel 1
// conv-as-GEMM: M = B*L, K = 448, N = 128.  A = xp rows (contiguous bf16),
// B = wt[n][k] (contiguous bf16x8 per frag, L2-resident). BN1+ReLU -> y bf16.
__global__ __launch_bounds__(256) void conv_bn_kernel(
    const short* __restrict__ xp, const short* __restrict__ wt,
    const float* __restrict__ cb, const float* __restrict__ g,
    const float* __restrict__ be, const float* __restrict__ mu,
    const float* __restrict__ va, short* __restrict__ y) {
    const int lane = threadIdx.x & 63;
    const int wid  = threadIdx.x >> 6;
    const int m0   = blockIdx.x * 64;
    const int nb   = wid * 32;
    const int q    = lane >> 4;
    const int ln   = lane & 15;

    const short* arow[4];
#pragma unroll
    for (int mt = 0; mt < 4; ++mt) {
        int m = m0 + mt * 16 + ln;
        int b = m >> 9, l = m & 511;           // m = b*512 + l
        arow[mt] = xp + (b * LPAD + l) * CIN;  // 448 contiguous bf16 (padded)
    }
    const short* brow[2];
#pragma unroll
    for (int nt = 0; nt < 2; ++nt)
        brow[nt] = wt + (size_t)(nb + nt * 16 + ln) * KC;

    f32x4 acc[4][2];
#pragma unroll
    for (int mt = 0; mt < 4; ++mt)
#pragma unroll
        for (int nt = 0; nt < 2; ++nt) acc[mt][nt] = (f32x4){0.f, 0.f, 0.f, 0.f};

#pragma unroll 2
    for (int kc = 0; kc < KC; kc += 32) {
        const int ko = kc + q * 8;
        bf16x8 a[4], bf[2];
#pragma unroll
        for (int mt = 0; mt < 4; ++mt) a[mt] = *(const bf16x8*)(arow[mt] + ko);
#pragma unroll
        for (int nt = 0; nt < 2; ++nt) bf[nt] = *(const bf16x8*)(brow[nt] + ko);
#pragma unroll
        for (int mt = 0; mt < 4; ++mt)
#pragma unroll
            for (int nt = 0; nt < 2; ++nt)
                acc[mt][nt] = __builtin_amdgcn_mfma_f32_16x16x32_bf16(
                    a[mt], bf[nt], acc[mt][nt], 0, 0, 0);
    }

#pragma unroll
    for (int nt = 0; nt < 2; ++nt) {
        const int n = nb + nt * 16 + ln;
        const float s  = g[n] * rsqrtf(va[n] + EPSV);
        const float b2 = s * (cb[n] - mu[n]) + be[n];
#pragma unroll
        for (int mt = 0; mt < 4; ++mt) {
            const int mbase = m0 + mt * 16 + q * 4;
#pragma unroll
            for (int r = 0; r < 4; ++r) {
                float v = fmaxf(acc[mt][nt][r] * s + b2, 0.0f);
                y[(size_t)(mbase + r) * FF + n] = f2bf(v);
            }
        }
    }
}

// ---------------------------------------------------------------- kernel 2
// locally-connected: one block per l. C(64x128) = A(64x896) @ W_l(896x128).
// W_l fp32 streamed via async global->LDS (16 B/lane), double-buffered BK=32.
__global__ __launch_bounds__(256) void local_bn_kernel(
    const short* __restrict__ y, const float* __restrict__ lw,
    const float* __restrict__ lb, const float* __restrict__ g,
    const float* __restrict__ be, const float* __restrict__ mu,
    const float* __restrict__ va, float* __restrict__ out) {
    __shared__ float wtile[2][BK * FF];        // 2 x 16 KB
    const int l    = blockIdx.x;
    const int lane = threadIdx.x & 63;
    const int wid  = threadIdx.x >> 6;
    const int nb   = wid * 32;
    const int q    = lane >> 4;
    const int ln   = lane & 15;

    const float* wl = lw + (size_t)l * (KL * FF);

    const short* arow[4];
#pragma unroll
    for (int mt = 0; mt < 4; ++mt)
        arow[mt] = y + (size_t)(mt * 16 + ln) * (LL * FF) + (size_t)l * FF;

    f32x4 acc[4][2];
#pragma unroll
    for (int mt = 0; mt < 4; ++mt)
#pragma unroll
        for (int nt = 0; nt < 2; ++nt) acc[mt][nt] = (f32x4){0.f, 0.f, 0.f, 0.f};

    // stage chunk 0
    {
        const float* src = wl;
#pragma unroll
        for (int r = 0; r < 4; ++r)
            g2lds16(src + (size_t)(r * 256 + wid * 64 + lane) * 4,
                    &wtile[0][(r * 256 + wid * 64) * 4]);
    }

    for (int c = 0; c < NCH; ++c) {
        __syncthreads();                       // drains vmcnt -> chunk c resident
        if (c + 1 < NCH) {                     // prefetch chunk c+1 into other buf
            const float* src = wl + (size_t)(c + 1) * (BK * FF);
            float* dst = wtile[(c + 1) & 1];
#pragma unroll
            for (int r = 0; r < 4; ++r)
                g2lds16(src + (size_t)(r * 256 + wid * 64 + lane) * 4,
                        &dst[(r * 256 + wid * 64) * 4]);
        }
        const float* wb = wtile[c & 1];
        const int ko = c * BK + q * 8;

        bf16x8 a[4];
#pragma unroll
        for (int mt = 0; mt < 4; ++mt) a[mt] = *(const bf16x8*)(arow[mt] + ko);

        bf16x8 bf[2];
#pragma unroll
        for (int nt = 0; nt < 2; ++nt) {
            const int n = nb + nt * 16 + ln;
#pragma unroll
            for (int j = 0; j < 8; ++j)
                bf[nt][j] = f2bf(wb[(q * 8 + j) * FF + n]);
        }
#pragma unroll
        for (int mt = 0; mt < 4; ++mt)
#pragma unroll
            for (int nt = 0; nt < 2; ++nt)
                acc[mt][nt] = __builtin_amdgcn_mfma_f32_16x16x32_bf16(
                    a[mt], bf[nt], acc[mt][nt], 0, 0, 0);
    }

    // epilogue: + local_b[l], BN2, ReLU, fp32 store
#pragma unroll
    for (int nt = 0; nt < 2; ++nt) {
        const int n = nb + nt * 16 + ln;
        const float s  = g[n] * rsqrtf(va[n] + EPSV);
        const float b2 = s * (lb[(size_t)l * FF + n] - mu[n]) + be[n];
#pragma unroll
        for (int mt = 0; mt < 4; ++mt) {
            const int bbase = mt * 16 + q * 4;
#pragma unroll
            for (int r = 0; r < 4; ++r) {
                float v = fmaxf(acc[mt][nt][r] * s + b2, 0.0f);
                out[(size_t)(bbase + r) * (OUTL * FF) + (size_t)l * FF + n] = v;
            }
        }
    }
}

// ---------------------------------------------------------------- launch
extern "C" void kernel_launch(void* const* d_in, const int* in_sizes, int n_in,
                              void* d_out, int out_size, void* d_ws, size_t ws_size,
                              hipStream_t stream) {
    const float* x       = (const float*)d_in[0];
    const float* conv_w  = (const float*)d_in[1];
    const float* conv_b  = (const float*)d_in[2];
    const float* bn1_g   = (const float*)d_in[3];
    const float* bn1_b   = (const float*)d_in[4];
    const float* bn1_m   = (const float*)d_in[5];
    const float* bn1_v   = (const float*)d_in[6];
    const float* local_w = (const float*)d_in[7];
    const float* local_b = (const float*)d_in[8];
    const float* bn2_g   = (const float*)d_in[9];
    const float* bn2_b   = (const float*)d_in[10];
    const float* bn2_m   = (const float*)d_in[11];
    const float* bn2_v   = (const float*)d_in[12];
    float* out = (float*)d_out;

    short* xp  = (short*)d_ws;                   // (64, 518, 64) bf16
    short* ybf = xp + (size_t)NPAD;              // (64, 512, 128) bf16
    short* wt  = ybf + (size_t)BB * LL * FF;     // (128, 448) bf16

    prep_kernel<<<PADB + WTB, 256, 0, stream>>>(x, conv_w, xp, wt);
    conv_bn_kernel<<<(BB * LL) / 64, 256, 0, stream>>>(
        xp, wt, conv_b, bn1_g, bn1_b, bn1_m, bn1_v, ybf);
    local_bn_kernel<<<OUTL, 256, 0, stream>>>(
        ybf, local_w, local_b, bn2_g, bn2_b, bn2_m, bn2_v, out);
}